// Round 12
// baseline (104.579 us; speedup 1.0000x reference)
//
#include <hip/hip_runtime.h>
#include <math.h>

#define Bn 32
#define Cn 256
#define Hn 64
#define Wn 64
#define HWn (Hn * Wn)      // 4096
#define MIDn 16
#define Kn 7
#define PADn 3

typedef float vf4 __attribute__((ext_vector_type(4)));

// -------- Kernel 1: per-(b,c) mean & max over H*W --------
// grid = 2048 blocks x 256 threads; ONE WAVE per (b,c) pair (4 pairs/block).
__global__ void pool_kernel(const float* __restrict__ x,
                            float* __restrict__ avg, float* __restrict__ mx) {
    int wave = threadIdx.x >> 6;
    int lane = threadIdx.x & 63;
    int pair = blockIdx.x * 4 + wave;          // (b,c) index 0..8191
    const float4* xp4 = (const float4*)(x + (size_t)pair * HWn);
    float s = 0.f, m = -INFINITY;
    #pragma unroll
    for (int k = 0; k < 16; ++k) {             // 1024 float4 / 64 lanes
        float4 v = xp4[lane + k * 64];
        s += v.x + v.y + v.z + v.w;
        m = fmaxf(m, fmaxf(fmaxf(v.x, v.y), fmaxf(v.z, v.w)));
    }
    #pragma unroll
    for (int off = 32; off > 0; off >>= 1) {
        s += __shfl_down(s, off);
        m = fmaxf(m, __shfl_down(m, off));
    }
    if (lane == 0) {
        avg[pair] = s * (1.f / (float)HWn);
        mx[pair]  = m;
    }
}

// -------- Kernel 2: per-block redundant MLP + per-pixel channel mean/max --------
// grid = B*32 = 1024 blocks, 512 threads = (32 float4-pixels) x (16 ch-groups of 16).
// 4 blocks/CU -> 32 waves/CU for max latency hiding on the strided x reads.
__global__ void featmlp_kernel(const float* __restrict__ x,
                               const float* __restrict__ avg, const float* __restrict__ mx,
                               const float* __restrict__ w1, const float* __restrict__ w2,
                               float* __restrict__ fmean, float* __restrict__ fmax,
                               float* __restrict__ ca) {
    int blk = blockIdx.x;
    int b = blk >> 5;                          // 32 blocks per batch
    int p0 = (blk & 31) * 128;                 // 128 pixels per block
    int t = threadIdx.x;

    // --- Phase A: ca[b,:] in LDS (tiny, redundant per block) ---
    __shared__ float sh[2 * MIDn];
    __shared__ float sca[Cn];
    if (t < 2 * MIDn) {
        int mm = t & (MIDn - 1);
        const float4* src = (const float4*)((t < MIDn ? avg : mx) + b * Cn);
        const float4* wr = (const float4*)(w1 + mm * Cn);
        float acc = 0.f;
        #pragma unroll
        for (int c4 = 0; c4 < Cn / 4; ++c4) {
            float4 v = src[c4], w = wr[c4];
            acc += v.x * w.x + v.y * w.y + v.z * w.z + v.w * w.w;
        }
        sh[t] = fmaxf(acc, 0.f);               // relu
    }
    __syncthreads();
    if (t < Cn) {
        float acc = 0.f;
        #pragma unroll
        for (int mm = 0; mm < MIDn; ++mm)
            acc += (sh[mm] + sh[MIDn + mm]) * w2[t * MIDn + mm];
        sca[t] = 1.f / (1.f + expf(-acc));
    }
    __syncthreads();
    if ((blk & 31) == 0 && t < Cn) ca[b * Cn + t] = sca[t];  // persist once/batch

    // --- Phase B: channel mean/max of x*ca; 16-way channel split ---
    int tx = t & 31;                           // float4 index (32 * 4 = 128 pixels)
    int ty = t >> 5;                           // channel group 0..15 (16 ch each)
    const float* xb = x + (size_t)b * Cn * HWn + p0 + tx * 4;
    float4 s = {0.f, 0.f, 0.f, 0.f};
    float4 m = {-INFINITY, -INFINITY, -INFINITY, -INFINITY};
    int c0 = ty * 16;
    for (int c = c0; c < c0 + 16; ++c) {
        float a = sca[c];
        float4 v = *(const float4*)(xb + (size_t)c * HWn);
        v.x *= a; v.y *= a; v.z *= a; v.w *= a;
        s.x += v.x; s.y += v.y; s.z += v.z; s.w += v.w;
        m.x = fmaxf(m.x, v.x); m.y = fmaxf(m.y, v.y);
        m.z = fmaxf(m.z, v.z); m.w = fmaxf(m.w, v.w);
    }
    __shared__ float4 lsum[16][32];
    __shared__ float4 lmax[16][32];
    lsum[ty][tx] = s; lmax[ty][tx] = m;
    __syncthreads();
    if (ty == 0) {
        #pragma unroll
        for (int q = 1; q < 16; ++q) {
            float4 s2 = lsum[q][tx], m2 = lmax[q][tx];
            s.x += s2.x; s.y += s2.y; s.z += s2.z; s.w += s2.w;
            m.x = fmaxf(m.x, m2.x); m.y = fmaxf(m.y, m2.y);
            m.z = fmaxf(m.z, m2.z); m.w = fmaxf(m.w, m2.w);
        }
        const float inv = 1.f / (float)Cn;
        float4 mean4 = {s.x * inv, s.y * inv, s.z * inv, s.w * inv};
        *(float4*)(fmean + b * HWn + p0 + tx * 4) = mean4;
        *(float4*)(fmax  + b * HWn + p0 + tx * 4) = m;
    }
}

// -------- Kernel 3: 7x7 conv on [2,H,W] feat + sigmoid -> smap[B,HW] --------
// grid = B*4 = 128 blocks (16-row stripes), 256 threads; stripe+halo staged in LDS
__global__ void conv_kernel(const float* __restrict__ fmean, const float* __restrict__ fmax,
                            const float* __restrict__ wsp, float* __restrict__ smap) {
    int blk = blockIdx.x;
    int b = blk >> 2;
    int r0 = (blk & 3) * 16;
    __shared__ float sm[22][64];
    __shared__ float sx[22][64];
    __shared__ float wgt[2 * Kn * Kn];
    int t = threadIdx.x;
    if (t < 2 * Kn * Kn) wgt[t] = wsp[t];
    for (int i = t; i < 22 * 64; i += 256) {
        int rr = r0 - PADn + (i >> 6);
        int cc = i & 63;
        float vm = 0.f, vx = 0.f;
        if (rr >= 0 && rr < Hn) {
            vm = fmean[b * HWn + rr * Wn + cc];
            vx = fmax[b * HWn + rr * Wn + cc];
        }
        sm[i >> 6][cc] = vm;
        sx[i >> 6][cc] = vx;
    }
    __syncthreads();
    for (int p = t; p < 16 * Wn; p += 256) {
        int h = p >> 6, w = p & 63;           // local row 0..15
        float acc = 0.f;
        #pragma unroll
        for (int kh = 0; kh < Kn; ++kh) {
            #pragma unroll
            for (int kw = 0; kw < Kn; ++kw) {
                int ww = w + kw - PADn;
                if (ww < 0 || ww >= Wn) continue;
                acc += sm[h + kh][ww] * wgt[kh * Kn + kw]
                     + sx[h + kh][ww] * wgt[Kn * Kn + kh * Kn + kw];
            }
        }
        smap[b * HWn + (r0 + h) * Wn + w] = 1.f / (1.f + expf(-acc));
    }
}

// -------- Kernel 4: out = x * ca * smap; one (b,c) plane per block (NT store) --------
__global__ void out_kernel(const float* __restrict__ x, const float* __restrict__ ca,
                           const float* __restrict__ smap, float* __restrict__ out) {
    int bc = blockIdx.x;
    int b = bc >> 8;
    float a = ca[bc];                          // block-uniform scalar
    const float4* xp = (const float4*)(x + (size_t)bc * HWn);
    const float4* sp = (const float4*)(smap + (size_t)b * HWn);
    vf4* op = (vf4*)out + (size_t)bc * (HWn / 4);
    int t = threadIdx.x;
    #pragma unroll
    for (int k = 0; k < 4; ++k) {
        int i = t + k * 256;
        float4 v = xp[i];
        float4 s4 = sp[i];
        vf4 o = {v.x * a * s4.x, v.y * a * s4.y, v.z * a * s4.z, v.w * a * s4.w};
        __builtin_nontemporal_store(o, op + i);
    }
}

extern "C" void kernel_launch(void* const* d_in, const int* in_sizes, int n_in,
                              void* d_out, int out_size, void* d_ws, size_t ws_size,
                              hipStream_t stream) {
    const float* x  = (const float*)d_in[0];
    const float* w1 = (const float*)d_in[1];
    const float* w2 = (const float*)d_in[2];
    const float* ws = (const float*)d_in[3];
    float* out = (float*)d_out;

    float* wsf   = (float*)d_ws;
    float* avg   = wsf;                      // B*C       = 8192
    float* mx    = avg + Bn * Cn;            // 8192
    float* ca    = mx + Bn * Cn;             // 8192
    float* fmean = ca + Bn * Cn;             // B*HW      = 131072
    float* fmax  = fmean + Bn * HWn;         // 131072
    float* smap  = fmax + Bn * HWn;          // 131072

    pool_kernel<<<2048, 256, 0, stream>>>(x, avg, mx);
    featmlp_kernel<<<Bn * 32, 512, 0, stream>>>(x, avg, mx, w1, w2, fmean, fmax, ca);
    conv_kernel<<<Bn * 4, 256, 0, stream>>>(fmean, fmax, ws, smap);
    out_kernel<<<Bn * Cn, 256, 0, stream>>>(x, ca, smap, out);
}

// Round 13
// 97.618 us; speedup vs baseline: 1.0713x; 1.0713x over previous
//
#include <hip/hip_runtime.h>
#include <math.h>

#define Bn 32
#define Cn 256
#define Hn 64
#define Wn 64
#define HWn (Hn * Wn)      // 4096
#define MIDn 16
#define Kn 7
#define PADn 3

typedef float vf4 __attribute__((ext_vector_type(4)));

// -------- Kernel 1: per-(b,c) mean & max over H*W --------
// grid = 2048 blocks x 256 threads; ONE WAVE per (b,c) pair (4 pairs/block).
__global__ void pool_kernel(const float* __restrict__ x,
                            float* __restrict__ avg, float* __restrict__ mx) {
    int wave = threadIdx.x >> 6;
    int lane = threadIdx.x & 63;
    int pair = blockIdx.x * 4 + wave;          // (b,c) index 0..8191
    const float4* xp4 = (const float4*)(x + (size_t)pair * HWn);
    float s = 0.f, m = -INFINITY;
    #pragma unroll
    for (int k = 0; k < 16; ++k) {             // 1024 float4 / 64 lanes
        float4 v = xp4[lane + k * 64];
        s += v.x + v.y + v.z + v.w;
        m = fmaxf(m, fmaxf(fmaxf(v.x, v.y), fmaxf(v.z, v.w)));
    }
    #pragma unroll
    for (int off = 32; off > 0; off >>= 1) {
        s += __shfl_down(s, off);
        m = fmaxf(m, __shfl_down(m, off));
    }
    if (lane == 0) {
        avg[pair] = s * (1.f / (float)HWn);
        mx[pair]  = m;
    }
}

// -------- Kernel 2: per-block redundant MLP + per-pixel channel mean/max --------
// grid = B*16 = 512 blocks, 512 threads = (64 float4-pixels) x (8 ch-groups of 32).
// EXACT R10 config (best measured).
__global__ void featmlp_kernel(const float* __restrict__ x,
                               const float* __restrict__ avg, const float* __restrict__ mx,
                               const float* __restrict__ w1, const float* __restrict__ w2,
                               float* __restrict__ fmean, float* __restrict__ fmax,
                               float* __restrict__ ca) {
    int blk = blockIdx.x;
    int b = blk >> 4;                          // 16 blocks per batch
    int ptile = (blk & 15) * 256;              // 256 pixels per block
    int t = threadIdx.x;

    // --- Phase A: ca[b,:] in LDS (tiny, redundant per block) ---
    __shared__ float sh[2 * MIDn];
    __shared__ float sca[Cn];
    if (t < 2 * MIDn) {
        int mm = t & (MIDn - 1);
        const float4* src = (const float4*)((t < MIDn ? avg : mx) + b * Cn);
        const float4* wr = (const float4*)(w1 + mm * Cn);
        float acc = 0.f;
        #pragma unroll
        for (int c4 = 0; c4 < Cn / 4; ++c4) {
            float4 v = src[c4], w = wr[c4];
            acc += v.x * w.x + v.y * w.y + v.z * w.z + v.w * w.w;
        }
        sh[t] = fmaxf(acc, 0.f);               // relu
    }
    __syncthreads();
    if (t < Cn) {
        float acc = 0.f;
        #pragma unroll
        for (int mm = 0; mm < MIDn; ++mm)
            acc += (sh[mm] + sh[MIDn + mm]) * w2[t * MIDn + mm];
        sca[t] = 1.f / (1.f + expf(-acc));
    }
    __syncthreads();
    if ((blk & 15) == 0 && t < Cn) ca[b * Cn + t] = sca[t];  // persist once/batch

    // --- Phase B: channel mean/max of x*ca; 8-way channel split ---
    int tx = t & 63;                           // float4 index (64 * 4 = 256 pixels)
    int ty = t >> 6;                           // channel eighth 0..7 (32 ch each)
    const float* xb = x + (size_t)b * Cn * HWn + ptile + tx * 4;
    float4 s = {0.f, 0.f, 0.f, 0.f};
    float4 m = {-INFINITY, -INFINITY, -INFINITY, -INFINITY};
    int c0 = ty * 32;
    for (int c = c0; c < c0 + 32; ++c) {
        float a = sca[c];
        float4 v = *(const float4*)(xb + (size_t)c * HWn);
        v.x *= a; v.y *= a; v.z *= a; v.w *= a;
        s.x += v.x; s.y += v.y; s.z += v.z; s.w += v.w;
        m.x = fmaxf(m.x, v.x); m.y = fmaxf(m.y, v.y);
        m.z = fmaxf(m.z, v.z); m.w = fmaxf(m.w, v.w);
    }
    __shared__ float4 lsum[8][64];
    __shared__ float4 lmax[8][64];
    lsum[ty][tx] = s; lmax[ty][tx] = m;
    __syncthreads();
    if (ty == 0) {
        #pragma unroll
        for (int q = 1; q < 8; ++q) {
            float4 s2 = lsum[q][tx], m2 = lmax[q][tx];
            s.x += s2.x; s.y += s2.y; s.z += s2.z; s.w += s2.w;
            m.x = fmaxf(m.x, m2.x); m.y = fmaxf(m.y, m2.y);
            m.z = fmaxf(m.z, m2.z); m.w = fmaxf(m.w, m2.w);
        }
        const float inv = 1.f / (float)Cn;
        float4 mean4 = {s.x * inv, s.y * inv, s.z * inv, s.w * inv};
        *(float4*)(fmean + b * HWn + ptile + tx * 4) = mean4;
        *(float4*)(fmax  + b * HWn + ptile + tx * 4) = m;
    }
}

// -------- Kernel 3: fused 7x7 conv (4-row stripe) + out = x*ca*sa --------
// grid = B*16 = 512 blocks, 512 threads. Per block: stage 10 halo rows (5 KB),
// conv 256 px (t<256, x1 redundancy), then stream 256 channels x 256 px with
// 1 KB-contiguous per-wave segments and NT stores.
__global__ void convout_kernel(const float* __restrict__ x, const float* __restrict__ ca,
                               const float* __restrict__ fmean, const float* __restrict__ fmax,
                               const float* __restrict__ wsp, float* __restrict__ out) {
    int blk = blockIdx.x;
    int b = blk >> 4;
    int r0 = (blk & 15) * 4;                   // output rows r0..r0+3
    int t = threadIdx.x;
    __shared__ float sm[10 * 64];
    __shared__ float sx[10 * 64];
    __shared__ float ssa[4 * 64];
    __shared__ float wgt[2 * Kn * Kn];
    if (t < 2 * Kn * Kn) wgt[t] = wsp[t];
    #pragma unroll
    for (int i = t; i < 10 * 64; i += 512) {   // stage rows r0-3 .. r0+6
        int rr = r0 - PADn + (i >> 6);
        int cc = i & 63;
        float vm = 0.f, vx = 0.f;
        if (rr >= 0 && rr < Hn) {
            vm = fmean[b * HWn + rr * Wn + cc];
            vx = fmax[b * HWn + rr * Wn + cc];
        }
        sm[i] = vm; sx[i] = vx;
    }
    __syncthreads();
    if (t < 4 * Wn) {
        int h = t >> 6, w = t & 63;            // local output row 0..3
        float acc = 0.f;
        #pragma unroll
        for (int kh = 0; kh < Kn; ++kh) {
            #pragma unroll
            for (int kw = 0; kw < Kn; ++kw) {
                int ww = w + kw - PADn;
                if (ww < 0 || ww >= Wn) continue;
                acc += sm[(h + kh) * 64 + ww] * wgt[kh * Kn + kw]
                     + sx[(h + kh) * 64 + ww] * wgt[Kn * Kn + kh * Kn + kw];
            }
        }
        ssa[t] = 1.f / (1.f + expf(-acc));
    }
    __syncthreads();
    const float4* sap = (const float4*)ssa;    // 64 float4 covering 256 px
    const float* cab = ca + b * Cn;
    size_t base = (size_t)b * Cn * HWn + r0 * Wn;   // x/out offset of stripe, c=0
    #pragma unroll 4
    for (int k = 0; k < 32; ++k) {
        int flat = t + k * 512;                // 0..16383
        int c = flat >> 6;                     // channel 0..255 (wave-uniform)
        int j = flat & 63;                     // float4 within stripe (1 KB/wave)
        float a = cab[c];
        float4 v = *((const float4*)(x + base + (size_t)c * HWn) + j);
        float4 s4 = sap[j];
        vf4 o = {v.x * a * s4.x, v.y * a * s4.y, v.z * a * s4.z, v.w * a * s4.w};
        __builtin_nontemporal_store(o, (vf4*)(out + base + (size_t)c * HWn) + j);
    }
}

extern "C" void kernel_launch(void* const* d_in, const int* in_sizes, int n_in,
                              void* d_out, int out_size, void* d_ws, size_t ws_size,
                              hipStream_t stream) {
    const float* x  = (const float*)d_in[0];
    const float* w1 = (const float*)d_in[1];
    const float* w2 = (const float*)d_in[2];
    const float* ws = (const float*)d_in[3];
    float* out = (float*)d_out;

    float* wsf   = (float*)d_ws;
    float* avg   = wsf;                      // B*C       = 8192
    float* mx    = avg + Bn * Cn;            // 8192
    float* ca    = mx + Bn * Cn;             // 8192
    float* fmean = ca + Bn * Cn;             // B*HW      = 131072
    float* fmax  = fmean + Bn * HWn;         // 131072

    pool_kernel<<<2048, 256, 0, stream>>>(x, avg, mx);
    featmlp_kernel<<<Bn * 16, 512, 0, stream>>>(x, avg, mx, w1, w2, fmean, fmax, ca);
    convout_kernel<<<Bn * 16, 512, 0, stream>>>(x, ca, fmean, fmax, ws, out);
}